// Round 12
// baseline (156.420 us; speedup 1.0000x reference)
//
#include <hip/hip_runtime.h>

// Problem constants (fixed by the reference).
#define T_LEN 4096
#define B_SZ  2
#define H_SZ  2048
#define NM    8            // N2 complex modes
#define BH    (B_SZ * H_SZ)

// clang vector type: REQUIRED for __builtin_nontemporal_store — HIP's
// float2 (HIP_vector_type class) is rejected by the builtin (r16 compile
// error). ext_vector_type is a true vector-of-float.
typedef float f32x2 __attribute__((ext_vector_type(2)));

// ---------------------------------------------------------------------------
// S4D via chunked linear recurrence (exact equivalent of the FFT conv):
//   S_n(t) = w_n * S_n(t-1) + x(t),  w_n = exp(dt*A_n)
//   out(t) = 2*Re( sum_n Cd_n * S_n(t) ) + D*x(t),  Cd = C*(w-1)/A
//
// Round 11 change under test: k1/k3 vectorized to 2 h-series per thread
// (f32x2 x/out, float4 states). Wave memory segments 256B -> 512B, half
// the ld/st instructions; theory: 256B-granular interleaved streams
// under-run HBM. launch_bounds(256,2): grid is 512 blocks = 2 blocks/CU
// resident, higher VGPR cap removes spill risk.
// k2 unchanged (256 blocks x 128 thr, BT=16).
// (Rounds 12-15: infra outage, control-confirmed. Round 16: HIP float2
//  swap broke nontemporal builtin -> compile error; f32x2 restored.)
// ---------------------------------------------------------------------------

template <int LC>
__global__ void __launch_bounds__(256, 2)
k1_chunk_end(const float* __restrict__ x,
             const float* __restrict__ log_dt,
             const float* __restrict__ Arl,
             const float* __restrict__ Aimp,
             float2* __restrict__ states) {
    int g  = blockIdx.x * blockDim.x + threadIdx.x;   // [C * BH/2)
    int hp = g % (H_SZ / 2);
    int h  = hp * 2;                                   // even h; thread owns h, h+1
    int b  = (g / (H_SZ / 2)) % B_SZ;
    int c  = g / (BH / 2);

    float dt0 = __expf(log_dt[h]);
    float dt1 = __expf(log_dt[h + 1]);
    float wr0[NM], wi0[NM], wr1[NM], wi1[NM];
#pragma unroll
    for (int n = 0; n < NM; ++n) {
        float ar0 = -__expf(Arl[h * NM + n]);
        float ai0 = Aimp[h * NM + n];
        float e0  = __expf(ar0 * dt0);
        wr0[n] = e0 * __cosf(ai0 * dt0);
        wi0[n] = e0 * __sinf(ai0 * dt0);
        float ar1 = -__expf(Arl[(h + 1) * NM + n]);
        float ai1 = Aimp[(h + 1) * NM + n];
        float e1  = __expf(ar1 * dt1);
        wr1[n] = e1 * __cosf(ai1 * dt1);
        wi1[n] = e1 * __sinf(ai1 * dt1);
    }

    float sr0[NM], si0[NM], sr1[NM], si1[NM];
#pragma unroll
    for (int n = 0; n < NM; ++n) { sr0[n] = si0[n] = sr1[n] = si1[n] = 0.f; }

    // x as f32x2 over h-pairs; stride between t's = BH/2 f32x2 elems.
    const f32x2* xp = (const f32x2*)(x + (size_t)c * LC * BH + b * H_SZ + h);

    constexpr int BT = 8;
    f32x2 buf[BT], nxt[BT];
#pragma unroll
    for (int i = 0; i < BT; ++i) buf[i] = xp[(size_t)i * (BH / 2)];

#pragma unroll
    for (int tb = 0; tb < LC / BT; ++tb) {
        if (tb + 1 < LC / BT) {
#pragma unroll
            for (int i = 0; i < BT; ++i)
                nxt[i] = xp[(size_t)((tb + 1) * BT + i) * (BH / 2)];
        }
#pragma unroll
        for (int i = 0; i < BT; ++i) {
            float x0 = buf[i].x, x1 = buf[i].y;
#pragma unroll
            for (int n = 0; n < NM; ++n) {
                float a0 = fmaf(wr0[n], sr0[n], fmaf(-wi0[n], si0[n], x0));
                float b0 = fmaf(wr0[n], si0[n], wi0[n] * sr0[n]);
                sr0[n] = a0; si0[n] = b0;
                float a1 = fmaf(wr1[n], sr1[n], fmaf(-wi1[n], si1[n], x1));
                float b1 = fmaf(wr1[n], si1[n], wi1[n] * sr1[n]);
                sr1[n] = a1; si1[n] = b1;
            }
        }
#pragma unroll
        for (int i = 0; i < BT; ++i) buf[i] = nxt[i];
    }

    // states[c][b][n][h] (float2 per state); h-pair => one float4 per mode.
    float4* st4 = (float4*)states;
#pragma unroll
    for (int n = 0; n < NM; ++n) {
        st4[((size_t)(c * B_SZ + b) * NM + n) * (H_SZ / 2) + hp] =
            make_float4(sr0[n], si0[n], sr1[n], si1[n]);
    }
}

// 128-thread blocks: BH*NM = 32768 threads -> 256 blocks, one per CU.
// BT=16 prefetch covers cross-XCD L2/L3 latency on the 256KB-stride walk.
template <int CC, int LC>
__global__ void __launch_bounds__(128, 4)
k2_carry_scan(const float* __restrict__ log_dt,
              const float* __restrict__ Arl,
              const float* __restrict__ Aimp,
              float2* __restrict__ states) {
    int g = blockIdx.x * blockDim.x + threadIdx.x;   // [BH * NM), h fastest
    int h = g % H_SZ;
    int n = (g / H_SZ) % NM;
    int b = g / (H_SZ * NM);

    float dt  = __expf(log_dt[h]);
    float Are = -__expf(Arl[h * NM + n]);
    float Aim = Aimp[h * NM + n];
    float er  = __expf(Are * dt * (float)LC);        // w^LC
    float ang = Aim * dt * (float)LC;
    float wr = er * __cosf(ang), wi = er * __sinf(ang);

    const size_t stride = (size_t)B_SZ * NM * H_SZ;  // chunk-to-chunk
    float2* base = states + ((size_t)b * NM + n) * H_SZ + h;

    float cr = 0.f, ci = 0.f;
    constexpr int BT = 16;
    float2 buf[BT], nxt[BT];
#pragma unroll
    for (int i = 0; i < BT; ++i) buf[i] = base[(size_t)i * stride];

#pragma unroll
    for (int cb = 0; cb < CC / BT; ++cb) {
        if (cb + 1 < CC / BT) {
#pragma unroll
            for (int i = 0; i < BT; ++i)
                nxt[i] = base[(size_t)((cb + 1) * BT + i) * stride];
        }
#pragma unroll
        for (int i = 0; i < BT; ++i) {
            int c = cb * BT + i;
            base[(size_t)c * stride] = make_float2(cr, ci);  // exclusive carry
            float ncr = fmaf(wr, cr, fmaf(-wi, ci, buf[i].x));
            float nci = fmaf(wr, ci, fmaf(wi, cr, buf[i].y));
            cr = ncr; ci = nci;
        }
#pragma unroll
        for (int i = 0; i < BT; ++i) buf[i] = nxt[i];
    }
}

template <int LC>
__global__ void __launch_bounds__(256, 2)
k3_output(const float* __restrict__ x,
          const float* __restrict__ Dp,
          const float* __restrict__ log_dt,
          const float* __restrict__ Arl,
          const float* __restrict__ Aimp,
          const float* __restrict__ Crep,
          const float* __restrict__ Cimp,
          const float2* __restrict__ states,
          float* __restrict__ out) {
    int g  = blockIdx.x * blockDim.x + threadIdx.x;   // [C * BH/2)
    int hp = g % (H_SZ / 2);
    int h  = hp * 2;
    int b  = (g / (H_SZ / 2)) % B_SZ;
    int c  = g / (BH / 2);

    float dt0 = __expf(log_dt[h]);
    float dt1 = __expf(log_dt[h + 1]);
    float wr0[NM], wi0[NM], wr1[NM], wi1[NM];
    float cdr0[NM], cdi0[NM], cdr1[NM], cdi1[NM];
#pragma unroll
    for (int n = 0; n < NM; ++n) {
        {
            float ar = -__expf(Arl[h * NM + n]);
            float ai = Aimp[h * NM + n];
            float e  = __expf(ar * dt0);
            float wrn = e * __cosf(ai * dt0);
            float win = e * __sinf(ai * dt0);
            wr0[n] = wrn; wi0[n] = win;
            float inv = 1.0f / (ar * ar + ai * ai);
            float tr = ((wrn - 1.f) * ar + win * ai) * inv;
            float ti = (win * ar - (wrn - 1.f) * ai) * inv;
            float Cre = Crep[h * NM + n], Cim = Cimp[h * NM + n];
            cdr0[n] = Cre * tr - Cim * ti;
            cdi0[n] = Cre * ti + Cim * tr;
        }
        {
            float ar = -__expf(Arl[(h + 1) * NM + n]);
            float ai = Aimp[(h + 1) * NM + n];
            float e  = __expf(ar * dt1);
            float wrn = e * __cosf(ai * dt1);
            float win = e * __sinf(ai * dt1);
            wr1[n] = wrn; wi1[n] = win;
            float inv = 1.0f / (ar * ar + ai * ai);
            float tr = ((wrn - 1.f) * ar + win * ai) * inv;
            float ti = (win * ar - (wrn - 1.f) * ai) * inv;
            float Cre = Crep[(h + 1) * NM + n], Cim = Cimp[(h + 1) * NM + n];
            cdr1[n] = Cre * tr - Cim * ti;
            cdi1[n] = Cre * ti + Cim * tr;
        }
    }

    // carry-in: states[c][b][n][h] as float4 per h-pair
    const float4* st4 = (const float4*)states;
    float sr0[NM], si0[NM], sr1[NM], si1[NM];
#pragma unroll
    for (int n = 0; n < NM; ++n) {
        float4 v = st4[((size_t)(c * B_SZ + b) * NM + n) * (H_SZ / 2) + hp];
        sr0[n] = v.x; si0[n] = v.y; sr1[n] = v.z; si1[n] = v.w;
    }

    float Dv0 = Dp[h], Dv1 = Dp[h + 1];
    const f32x2* xp = (const f32x2*)(x + (size_t)c * LC * BH + b * H_SZ + h);
    f32x2* op = (f32x2*)(out + (size_t)c * LC * BH + b * H_SZ + h);

    constexpr int BT = 4;
    f32x2 buf[BT], nxt[BT];
#pragma unroll
    for (int i = 0; i < BT; ++i) buf[i] = xp[(size_t)i * (BH / 2)];

#pragma unroll
    for (int tb = 0; tb < LC / BT; ++tb) {
        if (tb + 1 < LC / BT) {
#pragma unroll
            for (int i = 0; i < BT; ++i)
                nxt[i] = xp[(size_t)((tb + 1) * BT + i) * (BH / 2)];
        }
#pragma unroll
        for (int i = 0; i < BT; ++i) {
            float x0 = buf[i].x, x1 = buf[i].y;
            float y0 = 0.f, y1 = 0.f;
#pragma unroll
            for (int n = 0; n < NM; ++n) {
                float a0 = fmaf(wr0[n], sr0[n], fmaf(-wi0[n], si0[n], x0));
                float b0 = fmaf(wr0[n], si0[n], wi0[n] * sr0[n]);
                sr0[n] = a0; si0[n] = b0;
                y0 = fmaf(cdr0[n], a0, y0);
                y0 = fmaf(-cdi0[n], b0, y0);
                float a1 = fmaf(wr1[n], sr1[n], fmaf(-wi1[n], si1[n], x1));
                float b1 = fmaf(wr1[n], si1[n], wi1[n] * sr1[n]);
                sr1[n] = a1; si1[n] = b1;
                y1 = fmaf(cdr1[n], a1, y1);
                y1 = fmaf(-cdi1[n], b1, y1);
            }
            f32x2 ov;
            ov.x = fmaf(Dv0, x0, 2.0f * y0);
            ov.y = fmaf(Dv1, x1, 2.0f * y1);
            __builtin_nontemporal_store(ov, op + (size_t)(tb * BT + i) * (BH / 2));
        }
#pragma unroll
        for (int i = 0; i < BT; ++i) buf[i] = nxt[i];
    }
}

extern "C" void kernel_launch(void* const* d_in, const int* in_sizes, int n_in,
                              void* d_out, int out_size, void* d_ws, size_t ws_size,
                              hipStream_t stream) {
    const float* x      = (const float*)d_in[0];
    const float* Dp     = (const float*)d_in[1];
    const float* log_dt = (const float*)d_in[2];
    const float* Arl    = (const float*)d_in[3];
    const float* Aimp   = (const float*)d_in[4];
    const float* Cre    = (const float*)d_in[5];
    const float* Cim    = (const float*)d_in[6];
    float* out = (float*)d_out;
    float2* states = (float2*)d_ws;

    const size_t need64 = (size_t)64 * BH * NM * sizeof(float2);   // 16.8 MB

    if (ws_size >= need64) {
        constexpr int C = 64, LC = T_LEN / 64;      // LC = 64
        int total1 = C * BH / 2;                    // 131072 threads (h-pairs)
        k1_chunk_end<LC><<<total1 / 256, 256, 0, stream>>>(x, log_dt, Arl, Aimp, states);
        int total2 = BH * NM;                       // 32768 threads, 128/block
        k2_carry_scan<C, LC><<<total2 / 128, 128, 0, stream>>>(log_dt, Arl, Aimp, states);
        k3_output<LC><<<total1 / 256, 256, 0, stream>>>(x, Dp, log_dt, Arl, Aimp,
                                                        Cre, Cim, states, out);
    } else {
        constexpr int C = 32, LC = T_LEN / 32;      // LC = 128 (8.4 MB states)
        int total1 = C * BH / 2;
        k1_chunk_end<LC><<<total1 / 256, 256, 0, stream>>>(x, log_dt, Arl, Aimp, states);
        int total2 = BH * NM;
        k2_carry_scan<C, LC><<<total2 / 128, 128, 0, stream>>>(log_dt, Arl, Aimp, states);
        k3_output<LC><<<total1 / 256, 256, 0, stream>>>(x, Dp, log_dt, Arl, Aimp,
                                                        Cre, Cim, states, out);
    }
}

// Round 13
// 155.287 us; speedup vs baseline: 1.0073x; 1.0073x over previous
//
#include <hip/hip_runtime.h>

// Problem constants (fixed by the reference).
#define T_LEN 4096
#define B_SZ  2
#define H_SZ  2048
#define NM    8            // N2 complex modes
#define BH    (B_SZ * H_SZ)

// ---------------------------------------------------------------------------
// S4D via chunked linear recurrence (exact equivalent of the FFT conv):
//   S_n(t) = w_n * S_n(t-1) + x(t),  w_n = exp(dt*A_n)
//   out(t) = 2*Re( sum_n Cd_n * S_n(t) ) + D*x(t),  Cd = C*(w-1)/A
//
// Round 17: h-pair vectorization REFUTED (156.4 vs 152.1 scalar — halved
// occupancy outweighed wider segments). Reverted to scalar k1/k3 (16
// waves/CU). New change: states layout transposed [c][b][n][h] ->
// [b][n][c][h] so k2's chunk walk is stride-16KB (contiguous 1MB panel
// per (b,n)) instead of stride-256KB page-thrash. k1/k3 access cost
// unchanged (still one coalesced 512B wave segment per mode).
// ---------------------------------------------------------------------------

template <int C, int LC>
__global__ void __launch_bounds__(256, 4)
k1_chunk_end(const float* __restrict__ x,
             const float* __restrict__ log_dt,
             const float* __restrict__ Arl,
             const float* __restrict__ Aimp,
             float2* __restrict__ states) {
    int g = blockIdx.x * blockDim.x + threadIdx.x;   // [C * BH)
    int h = g % H_SZ;
    int b = (g / H_SZ) % B_SZ;
    int c = g / BH;

    float dt = __expf(log_dt[h]);
    float wr[NM], wi[NM];
#pragma unroll
    for (int n = 0; n < NM; ++n) {
        float ar  = -__expf(Arl[h * NM + n]);
        float ai  = Aimp[h * NM + n];
        float er  = __expf(ar * dt);
        float ang = ai * dt;
        wr[n] = er * __cosf(ang);
        wi[n] = er * __sinf(ang);
    }

    float sr[NM], si[NM];
#pragma unroll
    for (int n = 0; n < NM; ++n) { sr[n] = 0.f; si[n] = 0.f; }

    const float* xp = x + (size_t)c * LC * BH + b * H_SZ + h;

    constexpr int BT = 8;
    float buf[BT], nxt[BT];
#pragma unroll
    for (int i = 0; i < BT; ++i) buf[i] = xp[(size_t)i * BH];

#pragma unroll
    for (int tb = 0; tb < LC / BT; ++tb) {
        if (tb + 1 < LC / BT) {
#pragma unroll
            for (int i = 0; i < BT; ++i)
                nxt[i] = xp[(size_t)((tb + 1) * BT + i) * BH];
        }
#pragma unroll
        for (int i = 0; i < BT; ++i) {
            float xv = buf[i];
#pragma unroll
            for (int n = 0; n < NM; ++n) {
                float nsr = fmaf(wr[n], sr[n], fmaf(-wi[n], si[n], xv));
                float nsi = fmaf(wr[n], si[n], wi[n] * sr[n]);
                sr[n] = nsr; si[n] = nsi;
            }
        }
#pragma unroll
        for (int i = 0; i < BT; ++i) buf[i] = nxt[i];
    }

    // states[b][n][c][h] — coalesced across h within each mode's store.
#pragma unroll
    for (int n = 0; n < NM; ++n) {
        states[((size_t)(b * NM + n) * C + c) * H_SZ + h] =
            make_float2(sr[n], si[n]);
    }
}

// 128-thread blocks: BH*NM = 32768 threads -> 256 blocks, one per CU.
// With [b][n][c][h] layout the chunk walk is stride-16KB inside a
// contiguous 1MB (c,h) panel per (b,n) — L2-friendly streaming.
template <int CC, int LC>
__global__ void __launch_bounds__(128, 4)
k2_carry_scan(const float* __restrict__ log_dt,
              const float* __restrict__ Arl,
              const float* __restrict__ Aimp,
              float2* __restrict__ states) {
    int g = blockIdx.x * blockDim.x + threadIdx.x;   // [BH * NM), h fastest
    int h = g % H_SZ;
    int n = (g / H_SZ) % NM;
    int b = g / (H_SZ * NM);

    float dt  = __expf(log_dt[h]);
    float Are = -__expf(Arl[h * NM + n]);
    float Aim = Aimp[h * NM + n];
    // w^LC = exp(dt*A*LC)
    float er  = __expf(Are * dt * (float)LC);
    float ang = Aim * dt * (float)LC;
    float wr = er * __cosf(ang), wi = er * __sinf(ang);

    float2* base = states + (size_t)(b * NM + n) * CC * H_SZ + h;
    const size_t stride = (size_t)H_SZ;              // chunk-to-chunk: 16KB

    float cr = 0.f, ci = 0.f;
    constexpr int BT = 16;
    float2 buf[BT], nxt[BT];
#pragma unroll
    for (int i = 0; i < BT; ++i) buf[i] = base[(size_t)i * stride];

#pragma unroll
    for (int cb = 0; cb < CC / BT; ++cb) {
        if (cb + 1 < CC / BT) {
#pragma unroll
            for (int i = 0; i < BT; ++i)
                nxt[i] = base[(size_t)((cb + 1) * BT + i) * stride];
        }
#pragma unroll
        for (int i = 0; i < BT; ++i) {
            int c = cb * BT + i;
            base[(size_t)c * stride] = make_float2(cr, ci);  // exclusive carry
            float ncr = fmaf(wr, cr, fmaf(-wi, ci, buf[i].x));
            float nci = fmaf(wr, ci, fmaf(wi, cr, buf[i].y));
            cr = ncr; ci = nci;
        }
#pragma unroll
        for (int i = 0; i < BT; ++i) buf[i] = nxt[i];
    }
}

template <int C, int LC>
__global__ void __launch_bounds__(256, 4)
k3_output(const float* __restrict__ x,
          const float* __restrict__ Dp,
          const float* __restrict__ log_dt,
          const float* __restrict__ Arl,
          const float* __restrict__ Aimp,
          const float* __restrict__ Crep,
          const float* __restrict__ Cimp,
          const float2* __restrict__ states,
          float* __restrict__ out) {
    int g = blockIdx.x * blockDim.x + threadIdx.x;   // [C * BH)
    int h = g % H_SZ;
    int b = (g / H_SZ) % B_SZ;
    int c = g / BH;

    float dt = __expf(log_dt[h]);
    float wr[NM], wi[NM], cdr[NM], cdi[NM];
#pragma unroll
    for (int n = 0; n < NM; ++n) {
        float ar  = -__expf(Arl[h * NM + n]);
        float ai  = Aimp[h * NM + n];
        float er  = __expf(ar * dt);
        float ang = ai * dt;
        float wrn = er * __cosf(ang);
        float win = er * __sinf(ang);
        wr[n] = wrn; wi[n] = win;
        // Cd = (Cre + i*Cim) * (w - 1) / A  (divide via conj(A)/|A|^2)
        float inv = 1.0f / (ar * ar + ai * ai);
        float tr = ((wrn - 1.f) * ar + win * ai) * inv;
        float ti = (win * ar - (wrn - 1.f) * ai) * inv;
        float Cre = Crep[h * NM + n], Cim = Cimp[h * NM + n];
        cdr[n] = Cre * tr - Cim * ti;
        cdi[n] = Cre * ti + Cim * tr;
    }

    // carry-in: states[b][n][c][h]
    float sr[NM], si[NM];
#pragma unroll
    for (int n = 0; n < NM; ++n) {
        float2 v = states[((size_t)(b * NM + n) * C + c) * H_SZ + h];
        sr[n] = v.x; si[n] = v.y;
    }

    float Dv = Dp[h];
    const float* xp = x + (size_t)c * LC * BH + b * H_SZ + h;
    float* op = out + (size_t)c * LC * BH + b * H_SZ + h;

    constexpr int BT = 8;
    float buf[BT], nxt[BT];
#pragma unroll
    for (int i = 0; i < BT; ++i) buf[i] = xp[(size_t)i * BH];

#pragma unroll
    for (int tb = 0; tb < LC / BT; ++tb) {
        if (tb + 1 < LC / BT) {
#pragma unroll
            for (int i = 0; i < BT; ++i)
                nxt[i] = xp[(size_t)((tb + 1) * BT + i) * BH];
        }
#pragma unroll
        for (int i = 0; i < BT; ++i) {
            float xv = buf[i];
            float y = 0.f;
#pragma unroll
            for (int n = 0; n < NM; ++n) {
                float nsr = fmaf(wr[n], sr[n], fmaf(-wi[n], si[n], xv));
                float nsi = fmaf(wr[n], si[n], wi[n] * sr[n]);
                sr[n] = nsr; si[n] = nsi;
                y = fmaf(cdr[n], nsr, y);
                y = fmaf(-cdi[n], nsi, y);
            }
            float ov = fmaf(Dv, xv, 2.0f * y);
            __builtin_nontemporal_store(ov, op + (size_t)(tb * BT + i) * BH);
        }
#pragma unroll
        for (int i = 0; i < BT; ++i) buf[i] = nxt[i];
    }
}

extern "C" void kernel_launch(void* const* d_in, const int* in_sizes, int n_in,
                              void* d_out, int out_size, void* d_ws, size_t ws_size,
                              hipStream_t stream) {
    const float* x      = (const float*)d_in[0];
    const float* Dp     = (const float*)d_in[1];
    const float* log_dt = (const float*)d_in[2];
    const float* Arl    = (const float*)d_in[3];
    const float* Aimp   = (const float*)d_in[4];
    const float* Cre    = (const float*)d_in[5];
    const float* Cim    = (const float*)d_in[6];
    float* out = (float*)d_out;
    float2* states = (float2*)d_ws;

    const size_t need64 = (size_t)64 * BH * NM * sizeof(float2);   // 16.8 MB

    if (ws_size >= need64) {
        constexpr int C = 64, LC = T_LEN / 64;      // LC = 64
        int total1 = C * BH;                        // 262144 threads, 1024 blocks
        k1_chunk_end<C, LC><<<total1 / 256, 256, 0, stream>>>(x, log_dt, Arl, Aimp, states);
        int total2 = BH * NM;                       // 32768 threads, 128/block
        k2_carry_scan<C, LC><<<total2 / 128, 128, 0, stream>>>(log_dt, Arl, Aimp, states);
        k3_output<C, LC><<<total1 / 256, 256, 0, stream>>>(x, Dp, log_dt, Arl, Aimp,
                                                           Cre, Cim, states, out);
    } else {
        constexpr int C = 32, LC = T_LEN / 32;      // LC = 128 (8.4 MB states)
        int total1 = C * BH;
        k1_chunk_end<C, LC><<<total1 / 256, 256, 0, stream>>>(x, log_dt, Arl, Aimp, states);
        int total2 = BH * NM;
        k2_carry_scan<C, LC><<<total2 / 128, 128, 0, stream>>>(log_dt, Arl, Aimp, states);
        k3_output<C, LC><<<total1 / 256, 256, 0, stream>>>(x, Dp, log_dt, Arl, Aimp,
                                                           Cre, Cim, states, out);
    }
}